// Round 3
// baseline (223.629 us; speedup 1.0000x reference)
//
#include <hip/hip_runtime.h>
#include <hip/hip_bf16.h>

// MultiHeadedAttention fused pipeline for MI355X (gfx950), bf16 MFMA path.
// Stages: prep_w (weight transpose, LDS-tiled) -> QKV proj GEMM (fp32 A fused
// convert) -> flash attn -> O proj GEMM.  ws usage: 18 MB.
// R2: coalesced weight transpose; Xbf pass removed (convert fused into GEMM
// staging). attn/proj math byte-identical to R1 (audited, no HW data yet).

#define DEVI __device__ __forceinline__

typedef float f32x4 __attribute__((ext_vector_type(4)));
typedef __bf16 bf16x8 __attribute__((ext_vector_type(8)));

constexpr int S  = 2048;
constexpr int D  = 512;
constexpr int H  = 8;
constexpr int DK = 64;
constexpr int BATCH = 2;
constexpr int BS = BATCH * S;  // 4096

DEVI unsigned short f2bf(float f) {
  union { float f; unsigned u; } v; v.f = f;
  unsigned r = v.u + 0x7fffu + ((v.u >> 16) & 1u);  // round-to-nearest-even
  return (unsigned short)(r >> 16);
}

DEVI f32x4 mfma16(bf16x8 a, bf16x8 b, f32x4 c) {
  return __builtin_amdgcn_mfma_f32_16x16x32_bf16(a, b, c, 0, 0, 0);
}

DEVI bf16x8 ldg8(const unsigned short* p) { return *(const bf16x8*)p; }

// -------------------------------------------------------------- prep_w ----
// Wt [4][512][512] bf16 stored [n][d] (B^T layout), via 64x64 LDS transpose.
// g<3: Wt[g][h*64+kk][d] = W[h][d][kk]   (W shape [8][512][64])
// g=3: Wt[3][n][d]       = Wo[d][n]      (Wo shape [512][512])
// grid: 256 blocks = 4 g x (8 n-tiles x 8 d-tiles).
__global__ __launch_bounds__(256) void prep_w_kernel(
    const float* __restrict__ Wq, const float* __restrict__ Wk,
    const float* __restrict__ Wv, const float* __restrict__ Wo,
    unsigned short* __restrict__ Wt)
{
  __shared__ float T[64][65];
  int bid = blockIdx.x;
  int g = bid >> 6, t = bid & 63;
  int tn = t >> 3, td = t & 7;
  int n0 = tn * 64, d0 = td * 64;
  int tid = threadIdx.x;
  const float* src = (g == 0) ? Wq : (g == 1) ? Wk : (g == 2) ? Wv : Wo;

  // load 64(d) x 64(n) fp32 tile; source fastest dim is n (kk for g<3).
  #pragma unroll
  for (int cc = 0; cc < 4; ++cc) {
    int id = tid + cc * 256;               // 1024 float4 chunks
    int dd = id >> 4, f4 = (id & 15) * 4;
    const float* p = (g < 3)
      ? src + ((size_t)tn * D + d0 + dd) * DK + f4       // W[h=tn][d0+dd][kk=f4..]
      : src + (size_t)(d0 + dd) * D + n0 + f4;           // Wo[d0+dd][n0+f4..]
    float4 x = *(const float4*)p;
    T[dd][f4 + 0] = x.x; T[dd][f4 + 1] = x.y;
    T[dd][f4 + 2] = x.z; T[dd][f4 + 3] = x.w;
  }
  __syncthreads();

  // write transposed bf16: Wt[g][n0+nn][d0+dd], 16B chunks along d.
  #pragma unroll
  for (int cc = 0; cc < 2; ++cc) {
    int id = tid + cc * 256;               // 512 bf16x8 chunks
    int nn = id >> 3, ch = (id & 7) * 8;
    unsigned short o8[8];
    #pragma unroll
    for (int j = 0; j < 8; ++j) o8[j] = f2bf(T[ch + j][nn]);
    *(uint4*)&Wt[((size_t)g * D + n0 + nn) * D + d0 + ch] = *(const uint4*)o8;
  }
}

// ------------------------------------------------------------- QKV GEMM ----
// C[m][n] = sum_d A[m][d]*W[d][n] + bias[n].  A fp32 [4096][512] (converted
// to bf16 during LDS staging), Bt bf16 [n][d].
// z=0 -> Qb [bs][512]; z=1 -> Kb; z=2 -> Vt [(b*512+n)][2048] (transposed).
__global__ __launch_bounds__(256) void proj_qkv_kernel(
    const float* __restrict__ query, const float* __restrict__ key,
    const float* __restrict__ value, const unsigned short* __restrict__ Wt,
    const float* __restrict__ bq, const float* __restrict__ bk, const float* __restrict__ bv,
    unsigned short* __restrict__ Qb, unsigned short* __restrict__ Kb,
    unsigned short* __restrict__ Vtb)
{
  int z = blockIdx.z;
  const float* A = (z == 0) ? query : (z == 1) ? key : value;
  const unsigned short* Bt = Wt + (size_t)z * D * D;
  const float* bias = (z == 0) ? bq : (z == 1) ? bk : bv;

  __shared__ __align__(16) unsigned short At[128][72];     // +8 bf16 pad
  __shared__ __align__(16) unsigned short Btile[128][72];

  int tid = threadIdx.x;
  int w = tid >> 6, l = tid & 63;
  int g = l >> 4, c = l & 15;
  int wm = w >> 1, wn = w & 1;
  int m0 = blockIdx.y * 128, n0 = blockIdx.x * 128;

  f32x4 acc[4][4];
  #pragma unroll
  for (int i = 0; i < 4; ++i)
    #pragma unroll
    for (int j = 0; j < 4; ++j) acc[i][j] = f32x4{0.f, 0.f, 0.f, 0.f};

  for (int k0 = 0; k0 < D; k0 += 64) {
    __syncthreads();
    #pragma unroll
    for (int cc = 0; cc < 4; ++cc) {
      int id = tid + cc * 256;             // 1024 chunks of 8 elems per tile
      int row = id >> 3, ch = (id & 7) * 8;
      const float* p = A + (size_t)(m0 + row) * D + k0 + ch;
      float4 x0 = *(const float4*)p, x1 = *(const float4*)(p + 4);
      unsigned short o8[8] = { f2bf(x0.x), f2bf(x0.y), f2bf(x0.z), f2bf(x0.w),
                               f2bf(x1.x), f2bf(x1.y), f2bf(x1.z), f2bf(x1.w) };
      *(uint4*)&At[row][ch] = *(const uint4*)o8;
      *(bf16x8*)&Btile[row][ch] = ldg8(Bt + (size_t)(n0 + row) * D + k0 + ch);
    }
    __syncthreads();
    #pragma unroll
    for (int dc = 0; dc < 2; ++dc) {
      bf16x8 af[4], bv4[4];
      #pragma unroll
      for (int i = 0; i < 4; ++i)
        af[i] = *(const bf16x8*)&At[wm * 64 + i * 16 + c][dc * 32 + 8 * g];
      #pragma unroll
      for (int j = 0; j < 4; ++j)
        bv4[j] = *(const bf16x8*)&Btile[wn * 64 + j * 16 + c][dc * 32 + 8 * g];
      #pragma unroll
      for (int i = 0; i < 4; ++i)
        #pragma unroll
        for (int j = 0; j < 4; ++j)
          acc[i][j] = mfma16(af[i], bv4[j], acc[i][j]);
    }
  }

  #pragma unroll
  for (int i = 0; i < 4; ++i) {
    #pragma unroll
    for (int j = 0; j < 4; ++j) {
      int col = n0 + wn * 64 + j * 16 + c;
      float bb = bias[col];
      #pragma unroll
      for (int r = 0; r < 4; ++r) {
        int m = m0 + wm * 64 + i * 16 + 4 * g + r;
        unsigned short o = f2bf(acc[i][j][r] + bb);
        if (z == 0)      Qb[(size_t)m * D + col] = o;
        else if (z == 1) Kb[(size_t)m * D + col] = o;
        else {
          int b_ = m >> 11, s_ = m & 2047;
          Vtb[((size_t)b_ * D + col) * S + s_] = o;   // [b][h][dk][s]
        }
      }
    }
  }
}

// --------------------------------------------------------------- O GEMM ----
__global__ __launch_bounds__(256) void proj_o_kernel(
    const unsigned short* __restrict__ Ctx, const unsigned short* __restrict__ Bt,
    const float* __restrict__ bo, float* __restrict__ out)
{
  __shared__ __align__(16) unsigned short At[128][72];
  __shared__ __align__(16) unsigned short Btile[128][72];

  int tid = threadIdx.x;
  int w = tid >> 6, l = tid & 63;
  int g = l >> 4, c = l & 15;
  int wm = w >> 1, wn = w & 1;
  int m0 = blockIdx.y * 128, n0 = blockIdx.x * 128;

  f32x4 acc[4][4];
  #pragma unroll
  for (int i = 0; i < 4; ++i)
    #pragma unroll
    for (int j = 0; j < 4; ++j) acc[i][j] = f32x4{0.f, 0.f, 0.f, 0.f};

  for (int k0 = 0; k0 < D; k0 += 64) {
    __syncthreads();
    #pragma unroll
    for (int cc = 0; cc < 4; ++cc) {
      int id = tid + cc * 256;
      int row = id >> 3, ch = (id & 7) * 8;
      *(bf16x8*)&At[row][ch]    = ldg8(Ctx + (size_t)(m0 + row) * D + k0 + ch);
      *(bf16x8*)&Btile[row][ch] = ldg8(Bt  + (size_t)(n0 + row) * D + k0 + ch);
    }
    __syncthreads();
    #pragma unroll
    for (int dc = 0; dc < 2; ++dc) {
      bf16x8 af[4], bv4[4];
      #pragma unroll
      for (int i = 0; i < 4; ++i)
        af[i] = *(const bf16x8*)&At[wm * 64 + i * 16 + c][dc * 32 + 8 * g];
      #pragma unroll
      for (int j = 0; j < 4; ++j)
        bv4[j] = *(const bf16x8*)&Btile[wn * 64 + j * 16 + c][dc * 32 + 8 * g];
      #pragma unroll
      for (int i = 0; i < 4; ++i)
        #pragma unroll
        for (int j = 0; j < 4; ++j)
          acc[i][j] = mfma16(af[i], bv4[j], acc[i][j]);
    }
  }

  #pragma unroll
  for (int i = 0; i < 4; ++i) {
    #pragma unroll
    for (int j = 0; j < 4; ++j) {
      int col = n0 + wn * 64 + j * 16 + c;
      float bb = bo[col];
      #pragma unroll
      for (int r = 0; r < 4; ++r) {
        int m = m0 + wm * 64 + i * 16 + 4 * g + r;
        out[(size_t)m * D + col] = acc[i][j][r] + bb;
      }
    }
  }
}

// ----------------------------------------------------------- attention ----
// Flash-style. grid(32 qblocks, 16 bh), 256 thr = 4 waves x 16 q-rows each.
// K tile [64][64] and Vt tile [64 dk][64 s] staged in padded LDS (shared),
// P round-trips through per-wave private LDS to reach A-frag layout.
__global__ __launch_bounds__(256) void attn_kernel(
    const unsigned short* __restrict__ Qb, const unsigned short* __restrict__ Kb,
    const unsigned short* __restrict__ Vtb, const float* __restrict__ mask,
    unsigned short* __restrict__ Ctx)
{
  __shared__ __align__(16) unsigned short Kt[64][72];
  __shared__ __align__(16) unsigned short Vt[64][72];
  __shared__ __align__(16) unsigned short Pl[4][16][72];

  int tid = threadIdx.x;
  int w = tid >> 6, l = tid & 63;
  int g = l >> 4, c = l & 15;
  int bh = blockIdx.y, b = bh >> 3, h = bh & 7;
  int q0 = blockIdx.x * 64 + w * 16;

  // Q fragments held in registers for the whole kernel (A-frag: row=c, k=dc*32+8g).
  bf16x8 qf[2];
  #pragma unroll
  for (int dc = 0; dc < 2; ++dc)
    qf[dc] = ldg8(Qb + (size_t)(b * S + q0 + c) * D + h * DK + dc * 32 + 8 * g);

  float m_run[4], l_run[4];
  f32x4 o_acc[4];
  #pragma unroll
  for (int r = 0; r < 4; ++r) { m_run[r] = -1e30f; l_run[r] = 0.f; }
  #pragma unroll
  for (int nf = 0; nf < 4; ++nf) o_acc[nf] = f32x4{0.f, 0.f, 0.f, 0.f};

  for (int kb = 0; kb < S; kb += 64) {
    __syncthreads();
    #pragma unroll
    for (int cc = 0; cc < 2; ++cc) {
      int id = tid + cc * 256;             // 512 chunks each for K and V
      int row = id >> 3, ch = (id & 7) * 8;
      *(bf16x8*)&Kt[row][ch] = ldg8(Kb + (size_t)(b * S + kb + row) * D + h * DK + ch);
      *(bf16x8*)&Vt[row][ch] = ldg8(Vtb + ((size_t)bh * DK + row) * S + kb + ch);
    }
    __syncthreads();

    // S = Q K^T for this 64-wide tile (4 col-frags of 16).
    f32x4 sacc[4];
    #pragma unroll
    for (int fc = 0; fc < 4; ++fc) sacc[fc] = f32x4{0.f, 0.f, 0.f, 0.f};
    #pragma unroll
    for (int fc = 0; fc < 4; ++fc)
      #pragma unroll
      for (int dc = 0; dc < 2; ++dc) {
        bf16x8 kf = *(const bf16x8*)&Kt[fc * 16 + c][dc * 32 + 8 * g];
        sacc[fc] = mfma16(qf[dc], kf, sacc[fc]);
      }

    // mask + online softmax (rows live at q = 4g + r, cols at c + 16*fc)
    float p[4][4], mx[4];
    #pragma unroll
    for (int r = 0; r < 4; ++r) mx[r] = -1e30f;
    #pragma unroll
    for (int fc = 0; fc < 4; ++fc)
      #pragma unroll
      for (int r = 0; r < 4; ++r) {
        int qrow = q0 + 4 * g + r;
        float mv = mask[((size_t)b * S + qrow) * S + kb + fc * 16 + c];
        float sv = sacc[fc][r] * 0.125f;             // 1/sqrt(64)
        sv = sv * mv - 1e9f * (1.0f - mv);
        p[fc][r] = sv;
        mx[r] = fmaxf(mx[r], sv);
      }
    #pragma unroll
    for (int r = 0; r < 4; ++r) {
      float v = mx[r];
      v = fmaxf(v, __shfl_xor(v, 1, 64));
      v = fmaxf(v, __shfl_xor(v, 2, 64));
      v = fmaxf(v, __shfl_xor(v, 4, 64));
      v = fmaxf(v, __shfl_xor(v, 8, 64));
      float mnew = fmaxf(m_run[r], v);
      float corr = exp2f((m_run[r] - mnew) * 1.44269504f);
      m_run[r] = mnew;
      float rs = 0.f;
      #pragma unroll
      for (int fc = 0; fc < 4; ++fc) {
        float pe = exp2f((p[fc][r] - mnew) * 1.44269504f);
        p[fc][r] = pe;
        rs += pe;
      }
      rs += __shfl_xor(rs, 1, 64);
      rs += __shfl_xor(rs, 2, 64);
      rs += __shfl_xor(rs, 4, 64);
      rs += __shfl_xor(rs, 8, 64);
      l_run[r] = l_run[r] * corr + rs;
      #pragma unroll
      for (int nf = 0; nf < 4; ++nf) o_acc[nf][r] *= corr;
      #pragma unroll
      for (int fc = 0; fc < 4; ++fc)
        Pl[w][4 * g + r][fc * 16 + c] = f2bf(p[fc][r]);
    }

    // PV: ctx += P (16x32 A-frags from LDS) * V (32x16 B-frags from Vt).
    #pragma unroll
    for (int kc = 0; kc < 2; ++kc) {
      bf16x8 vf[4];
      #pragma unroll
      for (int nf = 0; nf < 4; ++nf)
        vf[nf] = *(const bf16x8*)&Vt[nf * 16 + c][kc * 32 + 8 * g];
      bf16x8 pf = *(const bf16x8*)&Pl[w][c][kc * 32 + 8 * g];
      #pragma unroll
      for (int nf = 0; nf < 4; ++nf)
        o_acc[nf] = mfma16(pf, vf[nf], o_acc[nf]);
    }
  }

  // epilogue: normalize and write ctx in [b][s][h*64+dk] (concat-head) layout.
  #pragma unroll
  for (int r = 0; r < 4; ++r) {
    float inv = 1.0f / l_run[r];
    int qrow = q0 + 4 * g + r;
    #pragma unroll
    for (int nf = 0; nf < 4; ++nf)
      Ctx[((size_t)b * S + qrow) * D + h * DK + nf * 16 + c] = f2bf(o_acc[nf][r] * inv);
  }
}

// ------------------------------------------------------------- launcher ----
extern "C" void kernel_launch(void* const* d_in, const int* in_sizes, int n_in,
                              void* d_out, int out_size, void* d_ws, size_t ws_size,
                              hipStream_t stream) {
  (void)in_sizes; (void)n_in; (void)out_size; (void)ws_size;
  const float* query = (const float*)d_in[0];
  const float* key   = (const float*)d_in[1];
  const float* value = (const float*)d_in[2];
  const float* mask  = (const float*)d_in[3];
  const float* Wq    = (const float*)d_in[4];
  const float* bq    = (const float*)d_in[5];
  const float* Wk    = (const float*)d_in[6];
  const float* bk    = (const float*)d_in[7];
  const float* Wv    = (const float*)d_in[8];
  const float* bv    = (const float*)d_in[9];
  const float* Wo    = (const float*)d_in[10];
  const float* bo    = (const float*)d_in[11];
  float* out = (float*)d_out;

  char* ws = (char*)d_ws;
  unsigned short* Wt  = (unsigned short*)(ws);                 //  2,097,152 B
  unsigned short* Qb  = (unsigned short*)(ws + 2097152);       //  4,194,304 B
  unsigned short* Kb  = (unsigned short*)(ws + 6291456);       //  4,194,304 B
  unsigned short* Vtb = (unsigned short*)(ws + 10485760);      //  4,194,304 B
  unsigned short* Ctx = (unsigned short*)(ws + 14680064);      //  4,194,304 B  (total 18 MB)

  hipLaunchKernelGGL(prep_w_kernel, dim3(256), dim3(256), 0, stream,
                     Wq, Wk, Wv, Wo, Wt);
  hipLaunchKernelGGL(proj_qkv_kernel, dim3(4, 32, 3), dim3(256), 0, stream,
                     query, key, value, Wt, bq, bk, bv, Qb, Kb, Vtb);
  hipLaunchKernelGGL(attn_kernel, dim3(32, 16), dim3(256), 0, stream,
                     Qb, Kb, Vtb, mask, Ctx);
  hipLaunchKernelGGL(proj_o_kernel, dim3(4, 32), dim3(256), 0, stream,
                     Ctx, Wt + 3 * D * D, bo, out);
}